// Round 8
// baseline (363.460 us; speedup 1.0000x reference)
//
#include <hip/hip_runtime.h>
#include <stdint.h>

typedef unsigned long long ull;
#define NN 8192
#define KK 32

// order-preserving float->u32 key. Positive NaN (canonical on AMD) maps above
// +inf automatically, matching numpy/jax "NaNs sort last" + [-K:] selection.
__device__ __forceinline__ ull make_key(float g, int idx) {
    uint32_t b = __float_as_uint(g);
    uint32_t k = b ^ (0x80000000u | (uint32_t)((int32_t)b >> 31));
    return ((ull)k << 32) | (uint32_t)idx;
}

__device__ __forceinline__ void cas_both(ull &a, ull &b) {  // a >= b after
    ull x = a, y = b;
    bool g = x < y;
    a = g ? y : x;
    b = g ? x : y;
}

// full bitonic sort, descending, SZ u64 in registers (static indexing only)
template <int SZ>
__device__ __forceinline__ void sortN_desc(ull (&c)[SZ]) {
#pragma unroll
    for (int k = 2; k <= SZ; k <<= 1) {
#pragma unroll
        for (int j = k >> 1; j > 0; j >>= 1) {
#pragma unroll
            for (int i = 0; i < SZ; ++i) {
                int l = i ^ j;
                if (l > i) {
                    if ((i & k) == 0) cas_both(c[i], c[l]);  // descending run
                    else              cas_both(c[l], c[i]);  // ascending run
                }
            }
        }
    }
}

// bitonic merge of a 32-element bitonic sequence -> fully descending
__device__ __forceinline__ void bmerge32_desc(ull (&c)[32]) {
#pragma unroll
    for (int j = 16; j > 0; j >>= 1) {
#pragma unroll
        for (int i = 0; i < 32; ++i) {
            if ((i & j) == 0) cas_both(c[i], c[i ^ j]);
        }
    }
}

// merge sorted-desc ch[32] into sorted-desc acc[32], keeping top-32
__device__ __forceinline__ void merge_into32(ull (&acc)[32], const ull (&ch)[32]) {
#pragma unroll
    for (int k = 0; k < 32; ++k) {
        ull a = acc[31 - k], b = ch[k];
        acc[31 - k] = a >= b ? a : b;  // pointwise max(desc, rev-desc) -> bitonic
    }
    bmerge32_desc(acc);
}

__device__ __forceinline__ void load_list32(const ull* __restrict__ src, int list,
                                            int j, ull (&ch)[32]) {
#pragma unroll
    for (int k = 0; k < 32; ++k)
        ch[k] = src[((size_t)list * 32 + k) * NN + j];
}

// ---------------- K1: row sums s[i] = sum_f x[i,f]
__global__ __launch_bounds__(256) void k_rowsum(const float* __restrict__ x,
                                                float* __restrict__ s) {
    int row  = blockIdx.x * 4 + (threadIdx.x >> 6);
    int lane = threadIdx.x & 63;
    float4 v = reinterpret_cast<const float4*>(x)[(size_t)row * 64 + lane];
    float sum = (v.x + v.y) + (v.z + v.w);
#pragma unroll
    for (int off = 1; off < 64; off <<= 1) sum += __shfl_xor(sum, off, 64);
    if (lane == 0) s[row] = sum;
}

// ---------------- K2: fused dist/probs write + per-column segment top-K
// + interleaved zeroing of the mask output.
// SINGLE CHANGE vs round 7: chunk 16->8 and __launch_bounds__(256,4) so
// VGPR <= 128 -> 16 waves/CU (was ~160 VGPR -> 8 waves/CU).
__global__ __launch_bounds__(256, 4) void k_fused(const float* __restrict__ q,
                                                  const float* __restrict__ s,
                                                  const float* __restrict__ tptr,
                                                  float* __restrict__ dist_out,
                                                  float* __restrict__ probs_out,
                                                  float* __restrict__ mask,
                                                  ull* __restrict__ cand,
                                                  int segr, int nthreads) {
    const int j = blockIdx.x * 256 + threadIdx.x;
    const int gtid = (blockIdx.y * (NN / 256) + blockIdx.x) * 256 + threadIdx.x;
    const float sj = s[j];
    const float temp = tptr[0];

    ull top[32];
#pragma unroll
    for (int k = 0; k < 32; ++k) top[k] = 0;  // real keys always > 0

    const int i0 = blockIdx.y * segr;
    for (int r = 0; r < segr; r += 8) {
        const int it = r >> 3;
        float qv[8];
#pragma unroll
        for (int u = 0; u < 8; ++u)
            qv[u] = q[(size_t)(i0 + r + u) * NN + j];

        ull ch[8];
#pragma unroll
        for (int u = 0; u < 8; ++u) {
            const int i = i0 + r + u;
            float diff = sj - s[i];            // s[i] wave-uniform
            float d = diff * diff;
            float pr = expf(-(temp * d)) + 1e-6f;  // probs, ref op order
            size_t off = (size_t)i * NN + j;
            __builtin_nontemporal_store(d, &dist_out[off]);
            __builtin_nontemporal_store(pr, &probs_out[off]);
            float a = logf(pr + 1e-6f);
            float b = logf(-logf(qv[u] + 1e-6f));
            ch[u] = make_key(a - b, i);
        }
        // interleaved mask zeroing: total NN*NN floats across the whole grid.
        // per thread: (segr/8) iters * 2 float4 = 64 floats... times nthreads.
        {
            float4* mask4 = (float4*)mask;
            const float4 z4 = make_float4(0.f, 0.f, 0.f, 0.f);
#pragma unroll
            for (int u = 0; u < 2; ++u)
                mask4[(size_t)(it * 2 + u) * nthreads + gtid] = z4;
        }

        sortN_desc<8>(ch);
        // cross step: pair top[24+u] (desc) with ch[7-u] (asc), keep max.
#pragma unroll
        for (int u = 0; u < 8; ++u) {
            ull a = top[24 + u], b = ch[7 - u];
            top[24 + u] = a >= b ? a : b;
        }
        bmerge32_desc(top);  // desc prefix + bitonic tail => bitonic overall
    }
    const size_t base = (size_t)blockIdx.y * KK * NN + j;
#pragma unroll
    for (int k = 0; k < KK; ++k) cand[base + (size_t)k * NN] = top[k];
}

// ---------------- K3: merge nseg sorted segment lists -> 4 per column
__global__ __launch_bounds__(256) void k_merge1(const ull* __restrict__ src,
                                                ull* __restrict__ dst,
                                                int lists_per_grp) {
    int gid = blockIdx.x * 256 + threadIdx.x;
    int j   = gid & (NN - 1);
    int grp = gid >> 13;  // 0..3
    ull acc[32];
    load_list32(src, grp * lists_per_grp, j, acc);
    for (int l = 1; l < lists_per_grp; ++l) {
        ull ch[32];
        load_list32(src, grp * lists_per_grp + l, j, ch);
        merge_into32(acc, ch);
    }
    const size_t base = (size_t)grp * KK * NN + j;
#pragma unroll
    for (int k = 0; k < KK; ++k) dst[base + (size_t)k * NN] = acc[k];
}

// ---------------- K4: final merge of 4 lists + emit edges/weights
__global__ __launch_bounds__(64) void k_final(const ull* __restrict__ src,
                                              float* __restrict__ out) {
    const int j = blockIdx.x * 64 + threadIdx.x;
    ull acc[32];
    load_list32(src, 0, j, acc);
#pragma unroll
    for (int l = 1; l < 4; ++l) {
        ull ch[32];
        load_list32(src, l, j, ch);
        merge_into32(acc, ch);
    }
    const size_t KN = (size_t)KK * NN;
    float* child  = out;
    float* parent = out + KN;
    float* wts    = out + 2 * KN;
#pragma unroll
    for (int k = 0; k < KK; ++k) {
        // ascending rank (N-K+k) == descending rank (K-1-k)
        uint32_t c = (uint32_t)acc[KK - 1 - k];
        child [(size_t)k * NN + j] = (float)c;
        parent[(size_t)k * NN + j] = (float)j;
        wts   [(size_t)k * NN + j] = 1.0f;
    }
}

// ---------------- K5: symmetric scatter of ones into mask (max parallelism)
__global__ __launch_bounds__(256) void k_scatter(const float* __restrict__ child,
                                                 float* __restrict__ mask) {
    int gid = blockIdx.x * 256 + threadIdx.x;  // 0 .. K*N-1
    int j = gid & (NN - 1);
    int k = gid >> 13;
    uint32_t c = (uint32_t)child[(size_t)k * NN + j];
    mask[(size_t)c * NN + j] = 1.0f;
    mask[(size_t)j * NN + c] = 1.0f;
}

extern "C" void kernel_launch(void* const* d_in, const int* in_sizes, int n_in,
                              void* d_out, int out_size, void* d_ws, size_t ws_size,
                              hipStream_t stream) {
    const float* x    = (const float*)d_in[0];
    const float* q    = (const float*)d_in[1];
    const float* tptr = (const float*)d_in[2];
    float* out = (float*)d_out;

    const size_t KN = (size_t)KK * NN;
    float* probs_out = out + 3 * KN;
    float* mask_out  = out + 3 * KN + (size_t)NN * NN;
    float* dist_out  = out + 3 * KN + 2 * (size_t)NN * NN;

    // workspace: s[N] | cand0[nseg lists] | cand1[4 lists]
    const size_t cand1_bytes = (size_t)NN * 4 * KK * 8;
    int nseg = 32;  // 1024 blocks
    if (ws_size < 65536 + (size_t)NN * 32 * KK * 8 + cand1_bytes) nseg = 16;
    const int segr = NN / nseg;
    const int nthreads = (NN / 256) * nseg * 256;
    float* s = (float*)d_ws;
    ull* cand0 = (ull*)((char*)d_ws + 65536);
    ull* cand1 = cand0 + (size_t)NN * nseg * KK;

    k_rowsum<<<NN / 4, 256, 0, stream>>>(x, s);
    k_fused<<<dim3(NN / 256, nseg), 256, 0, stream>>>(
        q, s, tptr, dist_out, probs_out, mask_out, cand0, segr, nthreads);
    k_merge1<<<(NN * 4) / 256, 256, 0, stream>>>(cand0, cand1, nseg / 4);
    k_final<<<NN / 64, 64, 0, stream>>>(cand1, out);
    k_scatter<<<(KK * NN) / 256, 256, 0, stream>>>(out, mask_out);
}

// Round 9
// 329.130 us; speedup vs baseline: 1.1043x; 1.1043x over previous
//
#include <hip/hip_runtime.h>
#include <stdint.h>

typedef unsigned long long ull;
typedef float __attribute__((ext_vector_type(4))) floatx4;
#define NN 8192
#define KK 32

// order-preserving float->u32 key. Positive NaN (canonical on AMD) maps above
// +inf automatically, matching numpy/jax "NaNs sort last" + [-K:] selection.
__device__ __forceinline__ ull make_key(float g, uint32_t idx) {
    uint32_t b = __float_as_uint(g);
    uint32_t k = b ^ (0x80000000u | (uint32_t)((int32_t)b >> 31));
    return ((ull)k << 32) | idx;
}

__device__ __forceinline__ void cas_both(ull &a, ull &b) {  // a >= b after
    ull x = a, y = b;
    bool g = x < y;
    a = g ? y : x;
    b = g ? x : y;
}

// full bitonic sort, descending, 16 u64 in registers (static indexing only)
__device__ __forceinline__ void sort16_desc(ull (&c)[16]) {
#pragma unroll
    for (int k = 2; k <= 16; k <<= 1) {
#pragma unroll
        for (int j = k >> 1; j > 0; j >>= 1) {
#pragma unroll
            for (int i = 0; i < 16; ++i) {
                int l = i ^ j;
                if (l > i) {
                    if ((i & k) == 0) cas_both(c[i], c[l]);  // descending run
                    else              cas_both(c[l], c[i]);  // ascending run
                }
            }
        }
    }
}

// bitonic merge of a 32-element bitonic sequence -> fully descending
__device__ __forceinline__ void bmerge32_desc(ull (&c)[32]) {
#pragma unroll
    for (int j = 16; j > 0; j >>= 1) {
#pragma unroll
        for (int i = 0; i < 32; ++i) {
            if ((i & j) == 0) cas_both(c[i], c[i ^ j]);
        }
    }
}

// merge sorted-desc ch[32] into sorted-desc acc[32], keeping top-32
__device__ __forceinline__ void merge_into32(ull (&acc)[32], const ull (&ch)[32]) {
#pragma unroll
    for (int k = 0; k < 32; ++k) {
        ull a = acc[31 - k], b = ch[k];
        acc[31 - k] = a >= b ? a : b;  // pointwise max(desc, rev-desc) -> bitonic
    }
    bmerge32_desc(acc);
}

__device__ __forceinline__ void load_list32(const ull* __restrict__ src, int list,
                                            int j, ull (&ch)[32]) {
#pragma unroll
    for (int k = 0; k < 32; ++k)
        ch[k] = src[((size_t)list * 32 + k) * NN + j];
}

// ---------------- K1: row sums s[i] = sum_f x[i,f]
__global__ __launch_bounds__(256) void k_rowsum(const float* __restrict__ x,
                                                float* __restrict__ s) {
    int row  = blockIdx.x * 4 + (threadIdx.x >> 6);
    int lane = threadIdx.x & 63;
    float4 v = reinterpret_cast<const float4*>(x)[(size_t)row * 64 + lane];
    float sum = (v.x + v.y) + (v.z + v.w);
#pragma unroll
    for (int off = 1; off < 64; off <<= 1) sum += __shfl_xor(sum, off, 64);
    if (lane == 0) s[row] = sum;
}

// ---------------- K2: fused dist/probs write + per-column segment top-K
// + interleaved zeroing of the mask output.
// vs R7 (345us): chunk16 network kept (53 ops/row) but q loaded in 2 batches
// of 8 so peak VGPR ~124 -> __launch_bounds__(256,4) = 16 waves/CU; u32
// offset addressing (all buffers < 268MB); NT mask-zero stores.
__global__ __launch_bounds__(256, 4) void k_fused(const float* __restrict__ q,
                                                  const float* __restrict__ s,
                                                  const float* __restrict__ tptr,
                                                  float* __restrict__ dist_out,
                                                  float* __restrict__ probs_out,
                                                  float* __restrict__ mask,
                                                  ull* __restrict__ cand,
                                                  int segr, int nthreads) {
    const uint32_t j = blockIdx.x * 256 + threadIdx.x;
    const uint32_t gtid =
        (blockIdx.y * (NN / 256) + blockIdx.x) * 256 + threadIdx.x;
    const float sj = s[j];
    const float temp = tptr[0];

    ull top[32];
#pragma unroll
    for (int k = 0; k < 32; ++k) top[k] = 0;  // real keys always > 0

    const uint32_t i0 = (uint32_t)blockIdx.y * (uint32_t)segr;
    for (uint32_t r = 0; r < (uint32_t)segr; r += 16) {
        const uint32_t it = r >> 4;
        const uint32_t ib = i0 + r;
        const uint32_t off0 = ib * NN + j;

        ull ch[16];
        // ---- half-batch A: rows ib+0 .. ib+7
        {
            float qv[8];
#pragma unroll
            for (uint32_t u = 0; u < 8; ++u) qv[u] = q[off0 + u * NN];
#pragma unroll
            for (uint32_t u = 0; u < 8; ++u) {
                float diff = sj - s[ib + u];  // block-uniform -> scalar load
                float d = diff * diff;
                float pr = expf(-(temp * d)) + 1e-6f;  // probs, ref op order
                uint32_t off = off0 + u * NN;
                __builtin_nontemporal_store(d, &dist_out[off]);
                __builtin_nontemporal_store(pr, &probs_out[off]);
                float a = logf(pr + 1e-6f);
                float b = logf(-logf(qv[u] + 1e-6f));
                ch[u] = make_key(a - b, ib + u);
            }
        }
        // ---- half-batch B: rows ib+8 .. ib+15
        {
            float qv[8];
#pragma unroll
            for (uint32_t u = 0; u < 8; ++u) qv[u] = q[off0 + (8 + u) * NN];
#pragma unroll
            for (uint32_t u = 0; u < 8; ++u) {
                float diff = sj - s[ib + 8 + u];
                float d = diff * diff;
                float pr = expf(-(temp * d)) + 1e-6f;
                uint32_t off = off0 + (8 + u) * NN;
                __builtin_nontemporal_store(d, &dist_out[off]);
                __builtin_nontemporal_store(pr, &probs_out[off]);
                float a = logf(pr + 1e-6f);
                float b = logf(-logf(qv[u] + 1e-6f));
                ch[8 + u] = make_key(a - b, ib + 8 + u);
            }
        }
        // interleaved mask zeroing (streaming NT): total NN*NN floats.
        {
            floatx4* mask4 = (floatx4*)mask;
            const floatx4 z4 = {0.f, 0.f, 0.f, 0.f};
#pragma unroll
            for (uint32_t u = 0; u < 4; ++u)
                __builtin_nontemporal_store(
                    z4, &mask4[(it * 4 + u) * (uint32_t)nthreads + gtid]);
        }

        sort16_desc(ch);
        // cross step: pair top[16+u] (desc) with ch[15-u] (asc), keep max.
#pragma unroll
        for (int u = 0; u < 16; ++u) {
            ull a = top[16 + u], b = ch[15 - u];
            top[16 + u] = a >= b ? a : b;
        }
        bmerge32_desc(top);  // desc prefix + bitonic tail => bitonic overall
    }
    const uint32_t base = (uint32_t)blockIdx.y * (KK * NN) + j;
#pragma unroll
    for (uint32_t k = 0; k < KK; ++k) cand[base + k * NN] = top[k];
}

// ---------------- K3: merge nseg sorted segment lists -> 4 per column
__global__ __launch_bounds__(256) void k_merge1(const ull* __restrict__ src,
                                                ull* __restrict__ dst,
                                                int lists_per_grp) {
    int gid = blockIdx.x * 256 + threadIdx.x;
    int j   = gid & (NN - 1);
    int grp = gid >> 13;  // 0..3
    ull acc[32];
    load_list32(src, grp * lists_per_grp, j, acc);
    for (int l = 1; l < lists_per_grp; ++l) {
        ull ch[32];
        load_list32(src, grp * lists_per_grp + l, j, ch);
        merge_into32(acc, ch);
    }
    const size_t base = (size_t)grp * KK * NN + j;
#pragma unroll
    for (int k = 0; k < KK; ++k) dst[base + (size_t)k * NN] = acc[k];
}

// ---------------- K4: final merge of 4 lists + emit edges/weights
__global__ __launch_bounds__(64) void k_final(const ull* __restrict__ src,
                                              float* __restrict__ out) {
    const int j = blockIdx.x * 64 + threadIdx.x;
    ull acc[32];
    load_list32(src, 0, j, acc);
#pragma unroll
    for (int l = 1; l < 4; ++l) {
        ull ch[32];
        load_list32(src, l, j, ch);
        merge_into32(acc, ch);
    }
    const size_t KN = (size_t)KK * NN;
    float* child  = out;
    float* parent = out + KN;
    float* wts    = out + 2 * KN;
#pragma unroll
    for (int k = 0; k < KK; ++k) {
        // ascending rank (N-K+k) == descending rank (K-1-k)
        uint32_t c = (uint32_t)acc[KK - 1 - k];
        child [(size_t)k * NN + j] = (float)c;
        parent[(size_t)k * NN + j] = (float)j;
        wts   [(size_t)k * NN + j] = 1.0f;
    }
}

// ---------------- K5: symmetric scatter of ones into mask (max parallelism)
__global__ __launch_bounds__(256) void k_scatter(const float* __restrict__ child,
                                                 float* __restrict__ mask) {
    int gid = blockIdx.x * 256 + threadIdx.x;  // 0 .. K*N-1
    int j = gid & (NN - 1);
    int k = gid >> 13;
    uint32_t c = (uint32_t)child[(size_t)k * NN + j];
    mask[(size_t)c * NN + j] = 1.0f;
    mask[(size_t)j * NN + c] = 1.0f;
}

extern "C" void kernel_launch(void* const* d_in, const int* in_sizes, int n_in,
                              void* d_out, int out_size, void* d_ws, size_t ws_size,
                              hipStream_t stream) {
    const float* x    = (const float*)d_in[0];
    const float* q    = (const float*)d_in[1];
    const float* tptr = (const float*)d_in[2];
    float* out = (float*)d_out;

    const size_t KN = (size_t)KK * NN;
    float* probs_out = out + 3 * KN;
    float* mask_out  = out + 3 * KN + (size_t)NN * NN;
    float* dist_out  = out + 3 * KN + 2 * (size_t)NN * NN;

    // workspace: s[N] | cand0[nseg lists] | cand1[4 lists]
    const size_t cand1_bytes = (size_t)NN * 4 * KK * 8;
    int nseg = 32;  // 1024 blocks
    if (ws_size < 65536 + (size_t)NN * 32 * KK * 8 + cand1_bytes) nseg = 16;
    const int segr = NN / nseg;
    const int nthreads = (NN / 256) * nseg * 256;
    float* s = (float*)d_ws;
    ull* cand0 = (ull*)((char*)d_ws + 65536);
    ull* cand1 = cand0 + (size_t)NN * nseg * KK;

    k_rowsum<<<NN / 4, 256, 0, stream>>>(x, s);
    k_fused<<<dim3(NN / 256, nseg), 256, 0, stream>>>(
        q, s, tptr, dist_out, probs_out, mask_out, cand0, segr, nthreads);
    k_merge1<<<(NN * 4) / 256, 256, 0, stream>>>(cand0, cand1, nseg / 4);
    k_final<<<NN / 64, 64, 0, stream>>>(cand1, out);
    k_scatter<<<(KK * NN) / 256, 256, 0, stream>>>(out, mask_out);
}